// Round 11
// baseline (173.115 us; speedup 1.0000x reference)
//
#include <hip/hip_runtime.h>
#include <hip/hip_cooperative_groups.h>

namespace cg = cooperative_groups;

#define Bn 16
#define Hn 512
#define Wn 512
#define RAD 24
#define WPR 16       // 32-bit words per row (Wn/32)
#define CGRID 512
#define NUNIT 4096   // 2 col-halves * 128 row-quads * 16 images
#define UPB 8        // units per block in coop path

typedef _Float16 h2 __attribute__((ext_vector_type(2)));

// vertical distance from column bit-words (5 words cover rows i-64..i+95)
__device__ __forceinline__ int dv_from(unsigned int W0, unsigned int W1,
                                       unsigned int W2, unsigned int W3,
                                       unsigned int W4, int q) {
  unsigned int mLE = (q == 31) ? W2 : (W2 & ((1u << (q + 1)) - 1u));
  int up = mLE ? (q - 31 + __clz(mLE))
               : (W1 ? (q + 1 + __clz(W1))
                     : (W0 ? (q + 33 + __clz(W0)) : 255));
  unsigned int Wd = W2 >> q;
  int down = Wd ? (__ffs(Wd) - 1)
                : (W3 ? (31 - q + __ffs(W3))
                      : (W4 ? (63 - q + __ffs(W4)) : 255));
  return min(up, down);
}

#define STEP(k)                                                              \
  {                                                                          \
    const h2 c1 = {(_Float16)(0.955f * (k)), (_Float16)(0.955f * (k))};      \
    const h2 c2 = {(_Float16)(0.4143f * (k)), (_Float16)(0.4143f * (k))};    \
    h2 vA = __builtin_elementwise_min(dvsA[tx + RAD - (k)],                  \
                                      dvsA[tx + RAD + (k)]);                 \
    h2 vB = __builtin_elementwise_min(dvsB[tx + RAD - (k)],                  \
                                      dvsB[tx + RAD + (k)]);                 \
    h2 fA = __builtin_elementwise_max(vA * BA2 + c1, vA * A2 + c2);          \
    h2 fB = __builtin_elementwise_max(vB * BA2 + c1, vB * A2 + c2);          \
    if ((k) & 1) {                                                           \
      a1 = __builtin_elementwise_min(a1, fA);                                \
      b1 = __builtin_elementwise_min(b1, fB);                                \
    } else {                                                                 \
      a0 = __builtin_elementwise_min(a0, fA);                                \
      b0 = __builtin_elementwise_min(b0, fB);                                \
    }                                                                        \
  }

#define CHECK(kn)                                                            \
  {                                                                          \
    h2 qa = __builtin_elementwise_min(a0, a1);                               \
    h2 qb = __builtin_elementwise_min(b0, b1);                               \
    float mm = fmaxf(fmaxf((float)qa.x, (float)qa.y),                        \
                     fmaxf((float)qb.x, (float)qb.y));                       \
    for (int s = 1; s < 64; s <<= 1) mm = fmaxf(mm, __shfl_xor(mm, s, 64));  \
    if (0.955f * (float)(kn) >= mm) goto done_lab;                           \
  }

#define WINDOW_LOOP                                                          \
  STEP(0) STEP(1) STEP(2) STEP(3) STEP(4) STEP(5) STEP(6) STEP(7) STEP(8)   \
  CHECK(9)                                                                   \
  STEP(9) STEP(10) STEP(11) STEP(12)                                         \
  CHECK(13)                                                                  \
  STEP(13) STEP(14) STEP(15) STEP(16)                                        \
  CHECK(17)                                                                  \
  STEP(17) STEP(18) STEP(19) STEP(20)                                        \
  CHECK(21)                                                                  \
  STEP(21) STEP(22) STEP(23) STEP(24)                                        \
done_lab:;

// ===========================================================================
// Cooperative single-kernel path. GRID=512 (2 blocks/CU — large margin).
// ===========================================================================
__global__ __launch_bounds__(256, 2) void k_all(
    const float* __restrict__ x, const float* __restrict__ tgt,
    unsigned int* __restrict__ mbits, unsigned int* __restrict__ cbits,
    float* __restrict__ partial, float* __restrict__ out) {
  __shared__ int nib[4608];
  __shared__ unsigned int lm[36][16];
  __shared__ unsigned int bnd[32][17];
  __shared__ h2 dvsA[304];
  __shared__ h2 dvsB[304];
  __shared__ float red[4];
  __shared__ double dred[256];

  const int g = blockIdx.x;
  const int tx = threadIdx.x;

  // prefetch all 8 units' x values (independent of phase A; streams with tgt)
  float L[UPB][4];
#pragma unroll
  for (int j = 0; j < UPB; ++j) {
    int u = g + j * CGRID;
    int cx = u & 1, by = (u >> 1) & 127, b = u >> 8;
    size_t row0 = ((size_t)b * Hn + 4 * by) * Wn;
    int col = cx * 256 + tx;
#pragma unroll
    for (int r = 0; r < 4; ++r) L[j][r] = x[row0 + (size_t)r * Wn + col];
  }

  // ---- phase A: blocks 0..255 binarize + morph + transpose ----
  if (g < 256) {
    const int w = g & 15, b = g >> 4;
    const int y0 = w * 32;
    const float4* t4 = (const float4*)(tgt + (size_t)b * Hn * Wn);

    for (int idx = tx; idx < 4608; idx += 256) {
      int r = idx >> 7, c4 = idx & 127;
      int y = y0 - 2 + r;
      int n = 0;
      if (y >= 0 && y < Hn) {
        float4 v = t4[(size_t)y * 128 + c4];
        n = (v.x > 0.5f ? 1 : 0) | (v.y > 0.5f ? 2 : 0) |
            (v.z > 0.5f ? 4 : 0) | (v.w > 0.5f ? 8 : 0);
      }
      nib[idx] = n;
    }
    __syncthreads();

    for (int idx = tx; idx < 576; idx += 256) {
      int r = idx >> 4, wi = idx & 15;
      unsigned int wv = 0;
#pragma unroll
      for (int c = 0; c < 8; ++c)
        wv |= ((unsigned int)nib[(r << 7) + (wi << 3) + c]) << (4 * c);
      lm[r][wi] = wv;
    }
    __syncthreads();

    for (int task = tx; task < 512; task += 256) {
      int rr = task >> 4, k = task & 15;
      unsigned int m[5][5];
#pragma unroll
      for (int dy = 0; dy < 5; ++dy)
#pragma unroll
        for (int dx = 0; dx < 5; ++dx) {
          int wi = k + dx - 2;
          m[dy][dx] = (wi >= 0 && wi < 16) ? lm[rr + dy][wi] : 0u;
        }
      unsigned int hb[5][3];
#pragma unroll
      for (int dy = 0; dy < 5; ++dy)
#pragma unroll
        for (int dx = 0; dx < 3; ++dx) {
          unsigned int l = m[dy][dx], c = m[dy][dx + 1], r2 = m[dy][dx + 2];
          hb[dy][dx] = c & ((c << 1) | (l >> 31)) & ((c >> 1) | (r2 << 31));
        }
      unsigned int D = 0;
#pragma unroll
      for (int dy = 1; dy <= 3; ++dy) {
        unsigned int C[3];
#pragma unroll
        for (int dx = 0; dx < 3; ++dx) {
          unsigned int E = hb[dy - 1][dx] & hb[dy][dx] & hb[dy + 1][dx];
          C[dx] = m[dy][dx + 1] & ~E;
        }
        D |= C[1] | ((C[1] << 1) | (C[0] >> 31)) | ((C[1] >> 1) | (C[2] << 31));
      }
      bnd[rr][k] = D;
      mbits[((size_t)b * Hn + y0 + rr) * WPR + k] = lm[2 + rr][k];
    }
    __syncthreads();

    for (int col = tx; col < 512; col += 256) {
      unsigned int bw = 0;
#pragma unroll
      for (int r = 0; r < 32; ++r)
        bw |= ((bnd[r][col >> 5] >> (col & 31)) & 1u) << r;
      cbits[((size_t)b * WPR + w) * Wn + col] = bw;
    }
  }

  // keep prefetched x live across the sync
#pragma unroll
  for (int j = 0; j < UPB; ++j)
#pragma unroll
    for (int r = 0; r < 4; ++r) asm volatile("" : "+v"(L[j][r]));

  cg::this_grid().sync();

  // ---- phase B: 8 loss tiles per block ----
  for (int j = 0; j < UPB; ++j) {
    const int u = g + j * CGRID;
    const int cx = u & 1, by = (u >> 1) & 127, b = u >> 8;
    const int i0 = 4 * by;
    const int c0 = cx * 256;
    const int wq = i0 >> 5, q = i0 & 31;
    const unsigned int* cw = cbits + (size_t)b * WPR * Wn;

    const int col = c0 + tx;
    const int wi = col >> 5, sh = col & 31;
    const size_t mrow = ((size_t)b * Hn + i0) * WPR + wi;
    unsigned int mw0 = mbits[mrow];
    unsigned int mw1 = mbits[mrow + WPR];
    unsigned int mw2 = mbits[mrow + 2 * WPR];
    unsigned int mw3 = mbits[mrow + 3 * WPR];

    for (int e = tx; e < 304; e += 256) {
      int c = c0 + e - RAD;
      int dv0 = 255, dv1 = 255, dv2 = 255, dv3 = 255;
      if (c >= 0 && c < Wn) {
        unsigned int W0 = (wq >= 2) ? cw[(size_t)(wq - 2) * Wn + c] : 0u;
        unsigned int W1 = (wq >= 1) ? cw[(size_t)(wq - 1) * Wn + c] : 0u;
        unsigned int W2 = cw[(size_t)wq * Wn + c];
        unsigned int W3 = (wq <= 14) ? cw[(size_t)(wq + 1) * Wn + c] : 0u;
        unsigned int W4 = (wq <= 13) ? cw[(size_t)(wq + 2) * Wn + c] : 0u;
        dv0 = dv_from(W0, W1, W2, W3, W4, q);
        dv1 = dv_from(W0, W1, W2, W3, W4, q + 1);
        dv2 = dv_from(W0, W1, W2, W3, W4, q + 2);
        dv3 = dv_from(W0, W1, W2, W3, W4, q + 3);
      }
      h2 pa, pb;
      pa.x = (_Float16)(float)dv0;
      pa.y = (_Float16)(float)dv1;
      pb.x = (_Float16)(float)dv2;
      pb.y = (_Float16)(float)dv3;
      dvsA[e] = pa;
      dvsB[e] = pb;
    }
    __syncthreads();

    const h2 A2 = {(_Float16)0.955f, (_Float16)0.955f};
    const h2 BA2 = {(_Float16)0.4143f, (_Float16)0.4143f};
    h2 a0 = {(_Float16)300.0f, (_Float16)300.0f};
    h2 a1 = a0, b0 = a0, b1 = a0;

    WINDOW_LOOP

    h2 amA = __builtin_elementwise_min(a0, a1);
    h2 amB = __builtin_elementwise_min(b0, b1);
    float d0 = (float)amA.x, d1 = (float)amA.y;
    float d2 = (float)amB.x, d3 = (float)amB.y;

    float w0 = __expf(d0 * (-1.0f / 3.0f)) + 0.1f;
    float w1 = __expf(d1 * (-1.0f / 3.0f)) + 0.1f;
    float w2 = __expf(d2 * (-1.0f / 3.0f)) + 0.1f;
    float w3 = __expf(d3 * (-1.0f / 3.0f)) + 0.1f;

    float t0 = (float)((mw0 >> sh) & 1u);
    float t1 = (float)((mw1 >> sh) & 1u);
    float t2 = (float)((mw2 >> sh) & 1u);
    float t3 = (float)((mw3 >> sh) & 1u);

    float L0 = fminf(fmaxf(L[j][0], -16.118095f), 16.118095f);
    float L1 = fminf(fmaxf(L[j][1], -16.118095f), 16.118095f);
    float L2 = fminf(fmaxf(L[j][2], -16.118095f), 16.118095f);
    float L3 = fminf(fmaxf(L[j][3], -16.118095f), 16.118095f);
    float bce0 = fmaxf(L0, 0.0f) - L0 * t0 + __logf(1.0f + __expf(-fabsf(L0)));
    float bce1 = fmaxf(L1, 0.0f) - L1 * t1 + __logf(1.0f + __expf(-fabsf(L1)));
    float bce2 = fmaxf(L2, 0.0f) - L2 * t2 + __logf(1.0f + __expf(-fabsf(L2)));
    float bce3 = fmaxf(L3, 0.0f) - L3 * t3 + __logf(1.0f + __expf(-fabsf(L3)));
    float val = bce0 * w0 + bce1 * w1 + bce2 * w2 + bce3 * w3;

#pragma unroll
    for (int s = 32; s; s >>= 1) val += __shfl_down(val, s, 64);
    if ((tx & 63) == 0) red[tx >> 6] = val;
    __syncthreads();
    if (tx == 0) partial[u] = red[0] + red[1] + red[2] + red[3];
    __syncthreads();
  }

  cg::this_grid().sync();

  // ---- phase C: block 0 deterministic double reduction ----
  if (g == 0) {
    double s = 0.0;
    for (int idx = tx; idx < NUNIT; idx += 256) s += (double)partial[idx];
    dred[tx] = s;
    __syncthreads();
    for (int st = 128; st; st >>= 1) {
      if (tx < st) dred[tx] += dred[tx + st];
      __syncthreads();
    }
    if (tx == 0) out[0] = (float)(dred[0] / (double)((size_t)Bn * Hn * Wn));
  }
}

// ===========================================================================
// Fallback path — exact round-9 three-kernel pipeline (known good, 32.3 us).
// ===========================================================================
__global__ __launch_bounds__(1024) void k_prep_fb(
    const float* __restrict__ tgt, unsigned int* __restrict__ mbits,
    unsigned int* __restrict__ cbits) {
  __shared__ int nib[4608];
  __shared__ unsigned int lm[36][16];
  __shared__ unsigned int bnd[32][17];
  const int w = blockIdx.x & 15, b = blockIdx.x >> 4;
  const int y0 = w * 32;
  const int t = threadIdx.x;
  const float4* t4 = (const float4*)(tgt + (size_t)b * Hn * Wn);

  for (int idx = t; idx < 4608; idx += 1024) {
    int r = idx >> 7, c4 = idx & 127;
    int y = y0 - 2 + r;
    int n = 0;
    if (y >= 0 && y < Hn) {
      float4 v = t4[(size_t)y * 128 + c4];
      n = (v.x > 0.5f ? 1 : 0) | (v.y > 0.5f ? 2 : 0) |
          (v.z > 0.5f ? 4 : 0) | (v.w > 0.5f ? 8 : 0);
    }
    nib[idx] = n;
  }
  __syncthreads();

  for (int idx = t; idx < 576; idx += 1024) {
    int r = idx >> 4, wi = idx & 15;
    unsigned int wv = 0;
#pragma unroll
    for (int c = 0; c < 8; ++c)
      wv |= ((unsigned int)nib[(r << 7) + (wi << 3) + c]) << (4 * c);
    lm[r][wi] = wv;
  }
  __syncthreads();

  if (t < 512) {
    int rr = t >> 4, k = t & 15;
    unsigned int m[5][5];
#pragma unroll
    for (int dy = 0; dy < 5; ++dy)
#pragma unroll
      for (int dx = 0; dx < 5; ++dx) {
        int wi = k + dx - 2;
        m[dy][dx] = (wi >= 0 && wi < 16) ? lm[rr + dy][wi] : 0u;
      }
    unsigned int hb[5][3];
#pragma unroll
    for (int dy = 0; dy < 5; ++dy)
#pragma unroll
      for (int dx = 0; dx < 3; ++dx) {
        unsigned int l = m[dy][dx], c = m[dy][dx + 1], r2 = m[dy][dx + 2];
        hb[dy][dx] = c & ((c << 1) | (l >> 31)) & ((c >> 1) | (r2 << 31));
      }
    unsigned int D = 0;
#pragma unroll
    for (int dy = 1; dy <= 3; ++dy) {
      unsigned int C[3];
#pragma unroll
      for (int dx = 0; dx < 3; ++dx) {
        unsigned int E = hb[dy - 1][dx] & hb[dy][dx] & hb[dy + 1][dx];
        C[dx] = m[dy][dx + 1] & ~E;
      }
      D |= C[1] | ((C[1] << 1) | (C[0] >> 31)) | ((C[1] >> 1) | (C[2] << 31));
    }
    bnd[rr][k] = D;
  } else {
    int task = t - 512;
    int r = task >> 4, wi = task & 15;
    mbits[((size_t)b * Hn + y0 + r) * WPR + wi] = lm[2 + r][wi];
  }
  __syncthreads();

  if (t < 512) {
    int col = t;
    unsigned int bw = 0;
#pragma unroll
    for (int r = 0; r < 32; ++r)
      bw |= ((bnd[r][col >> 5] >> (col & 31)) & 1u) << r;
    cbits[((size_t)b * WPR + w) * Wn + col] = bw;
  }
}

__global__ __launch_bounds__(256) void k_loss_fb(
    const float* __restrict__ x, const unsigned int* __restrict__ mbits,
    const unsigned int* __restrict__ cbits, float* __restrict__ partial) {
  __shared__ h2 dvsA[304];
  __shared__ h2 dvsB[304];
  __shared__ float red[4];
  const int cx = blockIdx.x, by = blockIdx.y, b = blockIdx.z;
  const int i0 = 4 * by;
  const int c0 = cx * 256;
  const int tx = threadIdx.x;
  const size_t row0 = ((size_t)b * Hn + i0) * Wn;
  const int wq = i0 >> 5, q = i0 & 31;
  const unsigned int* cw = cbits + (size_t)b * WPR * Wn;

  const int col = c0 + tx;
  float L0 = x[row0 + col];
  float L1 = x[row0 + Wn + col];
  float L2 = x[row0 + 2 * Wn + col];
  float L3 = x[row0 + 3 * Wn + col];
  const int wi = col >> 5, sh = col & 31;
  const size_t mrow = ((size_t)b * Hn + i0) * WPR + wi;
  unsigned int mw0 = mbits[mrow];
  unsigned int mw1 = mbits[mrow + WPR];
  unsigned int mw2 = mbits[mrow + 2 * WPR];
  unsigned int mw3 = mbits[mrow + 3 * WPR];

  for (int e = tx; e < 304; e += 256) {
    int c = c0 + e - RAD;
    int dv0 = 255, dv1 = 255, dv2 = 255, dv3 = 255;
    if (c >= 0 && c < Wn) {
      unsigned int W0 = (wq >= 2) ? cw[(size_t)(wq - 2) * Wn + c] : 0u;
      unsigned int W1 = (wq >= 1) ? cw[(size_t)(wq - 1) * Wn + c] : 0u;
      unsigned int W2 = cw[(size_t)wq * Wn + c];
      unsigned int W3 = (wq <= 14) ? cw[(size_t)(wq + 1) * Wn + c] : 0u;
      unsigned int W4 = (wq <= 13) ? cw[(size_t)(wq + 2) * Wn + c] : 0u;
      dv0 = dv_from(W0, W1, W2, W3, W4, q);
      dv1 = dv_from(W0, W1, W2, W3, W4, q + 1);
      dv2 = dv_from(W0, W1, W2, W3, W4, q + 2);
      dv3 = dv_from(W0, W1, W2, W3, W4, q + 3);
    }
    h2 pa, pb;
    pa.x = (_Float16)(float)dv0;
    pa.y = (_Float16)(float)dv1;
    pb.x = (_Float16)(float)dv2;
    pb.y = (_Float16)(float)dv3;
    dvsA[e] = pa;
    dvsB[e] = pb;
  }
  __syncthreads();

  const h2 A2 = {(_Float16)0.955f, (_Float16)0.955f};
  const h2 BA2 = {(_Float16)0.4143f, (_Float16)0.4143f};
  h2 a0 = {(_Float16)300.0f, (_Float16)300.0f};
  h2 a1 = a0, b0 = a0, b1 = a0;

  WINDOW_LOOP

  h2 amA = __builtin_elementwise_min(a0, a1);
  h2 amB = __builtin_elementwise_min(b0, b1);
  float d0 = (float)amA.x, d1 = (float)amA.y;
  float d2 = (float)amB.x, d3 = (float)amB.y;

  float w0 = __expf(d0 * (-1.0f / 3.0f)) + 0.1f;
  float w1 = __expf(d1 * (-1.0f / 3.0f)) + 0.1f;
  float w2 = __expf(d2 * (-1.0f / 3.0f)) + 0.1f;
  float w3 = __expf(d3 * (-1.0f / 3.0f)) + 0.1f;

  float t0 = (float)((mw0 >> sh) & 1u);
  float t1 = (float)((mw1 >> sh) & 1u);
  float t2 = (float)((mw2 >> sh) & 1u);
  float t3 = (float)((mw3 >> sh) & 1u);

  L0 = fminf(fmaxf(L0, -16.118095f), 16.118095f);
  L1 = fminf(fmaxf(L1, -16.118095f), 16.118095f);
  L2 = fminf(fmaxf(L2, -16.118095f), 16.118095f);
  L3 = fminf(fmaxf(L3, -16.118095f), 16.118095f);
  float bce0 = fmaxf(L0, 0.0f) - L0 * t0 + __logf(1.0f + __expf(-fabsf(L0)));
  float bce1 = fmaxf(L1, 0.0f) - L1 * t1 + __logf(1.0f + __expf(-fabsf(L1)));
  float bce2 = fmaxf(L2, 0.0f) - L2 * t2 + __logf(1.0f + __expf(-fabsf(L2)));
  float bce3 = fmaxf(L3, 0.0f) - L3 * t3 + __logf(1.0f + __expf(-fabsf(L3)));
  float val = bce0 * w0 + bce1 * w1 + bce2 * w2 + bce3 * w3;

#pragma unroll
  for (int s = 32; s; s >>= 1) val += __shfl_down(val, s, 64);
  if ((tx & 63) == 0) red[tx >> 6] = val;
  __syncthreads();
  if (tx == 0)
    partial[(((b << 7) + by) << 1) + cx] = red[0] + red[1] + red[2] + red[3];
}

__global__ __launch_bounds__(1024) void k_final_fb(
    const float* __restrict__ partial, float* __restrict__ out) {
  __shared__ double red[1024];
  double s = 0.0;
  for (int idx = threadIdx.x; idx < Bn * 256; idx += 1024)
    s += (double)partial[idx];
  red[threadIdx.x] = s;
  __syncthreads();
  for (int st = 512; st; st >>= 1) {
    if (threadIdx.x < st) red[threadIdx.x] += red[threadIdx.x + st];
    __syncthreads();
  }
  if (threadIdx.x == 0)
    out[0] = (float)(red[0] / (double)((size_t)Bn * Hn * Wn));
}

extern "C" void kernel_launch(void* const* d_in, const int* in_sizes, int n_in,
                              void* d_out, int out_size, void* d_ws, size_t ws_size,
                              hipStream_t stream) {
  const float* inputs = (const float*)d_in[0];
  const float* targets = (const float*)d_in[1];
  float* out = (float*)d_out;

  unsigned char* ws = (unsigned char*)d_ws;
  unsigned int* mbits = (unsigned int*)ws;                        // 512 KB
  unsigned int* cbits = (unsigned int*)(ws + (512 << 10));        // 512 KB
  float* partial = (float*)(ws + (1 << 20));                      // 16 KB

  void* args[] = {(void*)&inputs, (void*)&targets, (void*)&mbits,
                  (void*)&cbits,  (void*)&partial, (void*)&out};
  hipError_t e = hipLaunchCooperativeKernel((const void*)k_all, dim3(CGRID),
                                            dim3(256), args, 0, stream);
  if (e != hipSuccess) {
    (void)hipGetLastError();  // clear sticky error, take the 3-kernel path
    hipLaunchKernelGGL(k_prep_fb, dim3(Bn * 16), dim3(1024), 0, stream,
                       targets, mbits, cbits);
    dim3 blk(256, 1, 1), grd(2, Hn / 4, Bn);
    hipLaunchKernelGGL(k_loss_fb, grd, blk, 0, stream, inputs, mbits, cbits,
                       partial);
    hipLaunchKernelGGL(k_final_fb, dim3(1), dim3(1024), 0, stream, partial,
                       out);
  }
}

// Round 12
// 67.443 us; speedup vs baseline: 2.5668x; 2.5668x over previous
//
#include <hip/hip_runtime.h>

#define Bn 16
#define Hn 512
#define Wn 512
#define RAD 24
#define WPR 16  // 32-bit words per row (Wn/32)

typedef _Float16 h2 __attribute__((ext_vector_type(2)));

// ---------------------------------------------------------------------------
// K0: fused binarize + morphology + transpose (round-9 proven version).
// Block = (b, 32-row group w), 1024 threads. Also zeroes the accumulator.
// ---------------------------------------------------------------------------
__global__ __launch_bounds__(1024) void k_prep(
    const float* __restrict__ tgt, unsigned int* __restrict__ mbits,
    unsigned int* __restrict__ cbits, unsigned long long* __restrict__ acc) {
  __shared__ int nib[4608];             // 36 rows x 128 nibbles
  __shared__ unsigned int lm[36][16];   // mask words, rows y0-2..y0+33
  __shared__ unsigned int bnd[32][17];  // boundary bits, padded
  const int w = blockIdx.x & 15, b = blockIdx.x >> 4;
  const int y0 = w * 32;
  const int t = threadIdx.x;
  const float4* t4 = (const float4*)(tgt + (size_t)b * Hn * Wn);

  if (blockIdx.x == 0 && t == 0) *acc = 0ull;  // visible to k_loss via
                                               // kernel-end release

  for (int idx = t; idx < 4608; idx += 1024) {
    int r = idx >> 7, c4 = idx & 127;
    int y = y0 - 2 + r;
    int n = 0;
    if (y >= 0 && y < Hn) {
      float4 v = t4[(size_t)y * 128 + c4];
      n = (v.x > 0.5f ? 1 : 0) | (v.y > 0.5f ? 2 : 0) |
          (v.z > 0.5f ? 4 : 0) | (v.w > 0.5f ? 8 : 0);
    }
    nib[idx] = n;
  }
  __syncthreads();

  for (int idx = t; idx < 576; idx += 1024) {
    int r = idx >> 4, wi = idx & 15;
    unsigned int wv = 0;
#pragma unroll
    for (int c = 0; c < 8; ++c)
      wv |= ((unsigned int)nib[(r << 7) + (wi << 3) + c]) << (4 * c);
    lm[r][wi] = wv;
  }
  __syncthreads();

  if (t < 512) {
    int rr = t >> 4, k = t & 15;  // output row y0+rr, word k
    unsigned int m[5][5];
#pragma unroll
    for (int dy = 0; dy < 5; ++dy)
#pragma unroll
      for (int dx = 0; dx < 5; ++dx) {
        int wi = k + dx - 2;
        m[dy][dx] = (wi >= 0 && wi < 16) ? lm[rr + dy][wi] : 0u;
      }
    unsigned int hb[5][3];
#pragma unroll
    for (int dy = 0; dy < 5; ++dy)
#pragma unroll
      for (int dx = 0; dx < 3; ++dx) {
        unsigned int l = m[dy][dx], c = m[dy][dx + 1], r2 = m[dy][dx + 2];
        hb[dy][dx] = c & ((c << 1) | (l >> 31)) & ((c >> 1) | (r2 << 31));
      }
    unsigned int D = 0;
#pragma unroll
    for (int dy = 1; dy <= 3; ++dy) {
      unsigned int C[3];
#pragma unroll
      for (int dx = 0; dx < 3; ++dx) {
        unsigned int E = hb[dy - 1][dx] & hb[dy][dx] & hb[dy + 1][dx];
        C[dx] = m[dy][dx + 1] & ~E;
      }
      D |= C[1] | ((C[1] << 1) | (C[0] >> 31)) | ((C[1] >> 1) | (C[2] << 31));
    }
    bnd[rr][k] = D;
  } else {
    int task = t - 512;
    int r = task >> 4, wi = task & 15;
    mbits[((size_t)b * Hn + y0 + r) * WPR + wi] = lm[2 + r][wi];
  }
  __syncthreads();

  if (t < 512) {
    int col = t;
    unsigned int bw = 0;
#pragma unroll
    for (int r = 0; r < 32; ++r)
      bw |= ((bnd[r][col >> 5] >> (col & 31)) & 1u) << r;
    cbits[((size_t)b * WPR + w) * Wn + col] = bw;
  }
}

// ---------------------------------------------------------------------------
// vertical distance from column bit-words (5 words cover rows i-64..i+95)
// ---------------------------------------------------------------------------
__device__ __forceinline__ int dv_from(unsigned int W0, unsigned int W1,
                                       unsigned int W2, unsigned int W3,
                                       unsigned int W4, int q) {
  unsigned int mLE = (q == 31) ? W2 : (W2 & ((1u << (q + 1)) - 1u));
  int up = mLE ? (q - 31 + __clz(mLE))
               : (W1 ? (q + 1 + __clz(W1))
                     : (W0 ? (q + 33 + __clz(W0)) : 255));
  unsigned int Wd = W2 >> q;
  int down = Wd ? (__ffs(Wd) - 1)
                : (W3 ? (31 - q + __ffs(W3))
                      : (W4 ? (63 - q + __ffs(W4)) : 255));
  return min(up, down);
}

// ---------------------------------------------------------------------------
// K1: chamfer window, 4 rows/block, wave-uniform early exit, BCE, and the
// single-u64-atomic grand total: acc = (count << 52) | fixed-point sum.
// The 4096th arriving block writes the mean. No fences anywhere.
// ---------------------------------------------------------------------------
__global__ __launch_bounds__(256) void k_loss(
    const float* __restrict__ x, const unsigned int* __restrict__ mbits,
    const unsigned int* __restrict__ cbits,
    unsigned long long* __restrict__ acc, float* __restrict__ out) {
  __shared__ h2 dvsA[304];  // rows (i0, i0+1)
  __shared__ h2 dvsB[304];  // rows (i0+2, i0+3)
  __shared__ float red[4];
  const int cx = blockIdx.x, by = blockIdx.y, b = blockIdx.z;
  const int i0 = 4 * by;
  const int c0 = cx * 256;
  const int tx = threadIdx.x;
  const size_t row0 = ((size_t)b * Hn + i0) * Wn;
  const int wq = i0 >> 5, q = i0 & 31;  // q in {0,4,..,28}; q+3 <= 31
  const unsigned int* cw = cbits + (size_t)b * WPR * Wn;

  // issue x / mbits loads early; they retire under the window loop
  const int col = c0 + tx;
  float L0 = x[row0 + col];
  float L1 = x[row0 + Wn + col];
  float L2 = x[row0 + 2 * Wn + col];
  float L3 = x[row0 + 3 * Wn + col];
  const int wi = col >> 5, sh = col & 31;
  const size_t mrow = ((size_t)b * Hn + i0) * WPR + wi;
  unsigned int mw0 = mbits[mrow];
  unsigned int mw1 = mbits[mrow + WPR];
  unsigned int mw2 = mbits[mrow + 2 * WPR];
  unsigned int mw3 = mbits[mrow + 3 * WPR];

  for (int e = tx; e < 304; e += 256) {
    int c = c0 + e - RAD;
    int dv0 = 255, dv1 = 255, dv2 = 255, dv3 = 255;
    if (c >= 0 && c < Wn) {
      unsigned int W0 = (wq >= 2) ? cw[(size_t)(wq - 2) * Wn + c] : 0u;
      unsigned int W1 = (wq >= 1) ? cw[(size_t)(wq - 1) * Wn + c] : 0u;
      unsigned int W2 = cw[(size_t)wq * Wn + c];
      unsigned int W3 = (wq <= 14) ? cw[(size_t)(wq + 1) * Wn + c] : 0u;
      unsigned int W4 = (wq <= 13) ? cw[(size_t)(wq + 2) * Wn + c] : 0u;
      dv0 = dv_from(W0, W1, W2, W3, W4, q);
      dv1 = dv_from(W0, W1, W2, W3, W4, q + 1);
      dv2 = dv_from(W0, W1, W2, W3, W4, q + 2);
      dv3 = dv_from(W0, W1, W2, W3, W4, q + 3);
    }
    h2 pa, pb;
    pa.x = (_Float16)(float)dv0;
    pa.y = (_Float16)(float)dv1;
    pb.x = (_Float16)(float)dv2;
    pb.y = (_Float16)(float)dv3;
    dvsA[e] = pa;
    dvsB[e] = pb;
  }
  __syncthreads();

  const h2 A2 = {(_Float16)0.955f, (_Float16)0.955f};
  const h2 BA2 = {(_Float16)0.4143f, (_Float16)0.4143f};
  h2 a0 = {(_Float16)300.0f, (_Float16)300.0f};
  h2 a1 = a0, b0 = a0, b1 = a0;

#define STEP(k)                                                              \
  {                                                                          \
    const h2 c1 = {(_Float16)(0.955f * (k)), (_Float16)(0.955f * (k))};      \
    const h2 c2 = {(_Float16)(0.4143f * (k)), (_Float16)(0.4143f * (k))};    \
    h2 vA = __builtin_elementwise_min(dvsA[tx + RAD - (k)],                  \
                                      dvsA[tx + RAD + (k)]);                 \
    h2 vB = __builtin_elementwise_min(dvsB[tx + RAD - (k)],                  \
                                      dvsB[tx + RAD + (k)]);                 \
    h2 fA = __builtin_elementwise_max(vA * BA2 + c1, vA * A2 + c2);          \
    h2 fB = __builtin_elementwise_max(vB * BA2 + c1, vB * A2 + c2);          \
    if ((k) & 1) {                                                           \
      a1 = __builtin_elementwise_min(a1, fA);                                \
      b1 = __builtin_elementwise_min(b1, fB);                                \
    } else {                                                                 \
      a0 = __builtin_elementwise_min(a0, fA);                                \
      b0 = __builtin_elementwise_min(b0, fB);                                \
    }                                                                        \
  }

#define CHECK(kn)                                                            \
  {                                                                          \
    h2 qa = __builtin_elementwise_min(a0, a1);                               \
    h2 qb = __builtin_elementwise_min(b0, b1);                               \
    float mm = fmaxf(fmaxf((float)qa.x, (float)qa.y),                        \
                     fmaxf((float)qb.x, (float)qb.y));                       \
    for (int s = 1; s < 64; s <<= 1) mm = fmaxf(mm, __shfl_xor(mm, s, 64));  \
    if (0.955f * (float)(kn) >= mm) goto done_lab;                           \
  }

  STEP(0) STEP(1) STEP(2) STEP(3) STEP(4) STEP(5) STEP(6) STEP(7) STEP(8)
  CHECK(9)
  STEP(9) STEP(10) STEP(11) STEP(12)
  CHECK(13)
  STEP(13) STEP(14) STEP(15) STEP(16)
  CHECK(17)
  STEP(17) STEP(18) STEP(19) STEP(20)
  CHECK(21)
  STEP(21) STEP(22) STEP(23) STEP(24)
done_lab:;

  h2 amA = __builtin_elementwise_min(a0, a1);
  h2 amB = __builtin_elementwise_min(b0, b1);
  float d0 = (float)amA.x, d1 = (float)amA.y;
  float d2 = (float)amB.x, d3 = (float)amB.y;

  float w0 = __expf(d0 * (-1.0f / 3.0f)) + 0.1f;
  float w1 = __expf(d1 * (-1.0f / 3.0f)) + 0.1f;
  float w2 = __expf(d2 * (-1.0f / 3.0f)) + 0.1f;
  float w3 = __expf(d3 * (-1.0f / 3.0f)) + 0.1f;

  float t0 = (float)((mw0 >> sh) & 1u);
  float t1 = (float)((mw1 >> sh) & 1u);
  float t2 = (float)((mw2 >> sh) & 1u);
  float t3 = (float)((mw3 >> sh) & 1u);

  L0 = fminf(fmaxf(L0, -16.118095f), 16.118095f);
  L1 = fminf(fmaxf(L1, -16.118095f), 16.118095f);
  L2 = fminf(fmaxf(L2, -16.118095f), 16.118095f);
  L3 = fminf(fmaxf(L3, -16.118095f), 16.118095f);
  float bce0 = fmaxf(L0, 0.0f) - L0 * t0 + __logf(1.0f + __expf(-fabsf(L0)));
  float bce1 = fmaxf(L1, 0.0f) - L1 * t1 + __logf(1.0f + __expf(-fabsf(L1)));
  float bce2 = fmaxf(L2, 0.0f) - L2 * t2 + __logf(1.0f + __expf(-fabsf(L2)));
  float bce3 = fmaxf(L3, 0.0f) - L3 * t3 + __logf(1.0f + __expf(-fabsf(L3)));
  float val = bce0 * w0 + bce1 * w1 + bce2 * w2 + bce3 * w3;

#pragma unroll
  for (int s = 32; s; s >>= 1) val += __shfl_down(val, s, 64);
  if ((tx & 63) == 0) red[tx >> 6] = val;
  __syncthreads();
  if (tx == 0) {
    float s = red[0] + red[1] + red[2] + red[3];
    // fixed-point (2^20) partial; sum over 4096 blocks < 2^52 (no overflow
    // into the count field). Integer atomic add -> order-independent result.
    unsigned long long qv =
        (unsigned long long)__double2ll_rn((double)s * 1048576.0);
    unsigned long long old = atomicAdd(acc, qv + (1ull << 52));
    if ((old >> 52) == 4095ull) {  // we are the last of 4096 blocks
      unsigned long long sum = (old & ((1ull << 52) - 1ull)) + qv;
      out[0] =
          (float)((double)sum / (1048576.0 * (double)((size_t)Bn * Hn * Wn)));
    }
  }
}

extern "C" void kernel_launch(void* const* d_in, const int* in_sizes, int n_in,
                              void* d_out, int out_size, void* d_ws, size_t ws_size,
                              hipStream_t stream) {
  const float* inputs = (const float*)d_in[0];
  const float* targets = (const float*)d_in[1];
  float* out = (float*)d_out;

  unsigned char* ws = (unsigned char*)d_ws;
  unsigned int* mbits = (unsigned int*)ws;                        // 512 KB
  unsigned int* cbits = (unsigned int*)(ws + (512 << 10));        // 512 KB
  unsigned long long* acc = (unsigned long long*)(ws + (1 << 20));

  hipLaunchKernelGGL(k_prep, dim3(Bn * 16), dim3(1024), 0, stream, targets,
                     mbits, cbits, acc);
  {
    dim3 blk(256, 1, 1), grd(2, Hn / 4, Bn);
    hipLaunchKernelGGL(k_loss, grd, blk, 0, stream, inputs, mbits, cbits, acc,
                       out);
  }
}

// Round 13
// 30.863 us; speedup vs baseline: 5.6092x; 2.1853x over previous
//
#include <hip/hip_runtime.h>

#define Bn 16
#define Hn 512
#define Wn 512
#define RAD 24
#define WPR 16  // 32-bit words per row (Wn/32)

typedef _Float16 h2 __attribute__((ext_vector_type(2)));

// ---------------------------------------------------------------------------
// K0: fused binarize + morphology + transpose (round-9 proven version).
// Block = (b, 32-row group w), 1024 threads. Block 0 zeroes the atomic tree.
// ---------------------------------------------------------------------------
__global__ __launch_bounds__(1024) void k_prep(
    const float* __restrict__ tgt, unsigned int* __restrict__ mbits,
    unsigned int* __restrict__ cbits, unsigned long long* __restrict__ grp,
    unsigned int* __restrict__ supercnt) {
  __shared__ int nib[4608];             // 36 rows x 128 nibbles
  __shared__ unsigned int lm[36][16];   // mask words, rows y0-2..y0+33
  __shared__ unsigned int bnd[32][17];  // boundary bits, padded
  const int w = blockIdx.x & 15, b = blockIdx.x >> 4;
  const int y0 = w * 32;
  const int t = threadIdx.x;
  const float4* t4 = (const float4*)(tgt + (size_t)b * Hn * Wn);

  if (blockIdx.x == 0) {  // zero atomic tree (visible via kernel-end release)
    if (t < 64) grp[t * 8] = 0ull;
    else if (t == 64) *supercnt = 0u;
  }

  for (int idx = t; idx < 4608; idx += 1024) {
    int r = idx >> 7, c4 = idx & 127;
    int y = y0 - 2 + r;
    int n = 0;
    if (y >= 0 && y < Hn) {
      float4 v = t4[(size_t)y * 128 + c4];
      n = (v.x > 0.5f ? 1 : 0) | (v.y > 0.5f ? 2 : 0) |
          (v.z > 0.5f ? 4 : 0) | (v.w > 0.5f ? 8 : 0);
    }
    nib[idx] = n;
  }
  __syncthreads();

  for (int idx = t; idx < 576; idx += 1024) {
    int r = idx >> 4, wi = idx & 15;
    unsigned int wv = 0;
#pragma unroll
    for (int c = 0; c < 8; ++c)
      wv |= ((unsigned int)nib[(r << 7) + (wi << 3) + c]) << (4 * c);
    lm[r][wi] = wv;
  }
  __syncthreads();

  if (t < 512) {
    int rr = t >> 4, k = t & 15;  // output row y0+rr, word k
    unsigned int m[5][5];
#pragma unroll
    for (int dy = 0; dy < 5; ++dy)
#pragma unroll
      for (int dx = 0; dx < 5; ++dx) {
        int wi = k + dx - 2;
        m[dy][dx] = (wi >= 0 && wi < 16) ? lm[rr + dy][wi] : 0u;
      }
    unsigned int hb[5][3];
#pragma unroll
    for (int dy = 0; dy < 5; ++dy)
#pragma unroll
      for (int dx = 0; dx < 3; ++dx) {
        unsigned int l = m[dy][dx], c = m[dy][dx + 1], r2 = m[dy][dx + 2];
        hb[dy][dx] = c & ((c << 1) | (l >> 31)) & ((c >> 1) | (r2 << 31));
      }
    unsigned int D = 0;
#pragma unroll
    for (int dy = 1; dy <= 3; ++dy) {
      unsigned int C[3];
#pragma unroll
      for (int dx = 0; dx < 3; ++dx) {
        unsigned int E = hb[dy - 1][dx] & hb[dy][dx] & hb[dy + 1][dx];
        C[dx] = m[dy][dx + 1] & ~E;
      }
      D |= C[1] | ((C[1] << 1) | (C[0] >> 31)) | ((C[1] >> 1) | (C[2] << 31));
    }
    bnd[rr][k] = D;
  } else {
    int task = t - 512;
    int r = task >> 4, wi = task & 15;
    mbits[((size_t)b * Hn + y0 + r) * WPR + wi] = lm[2 + r][wi];
  }
  __syncthreads();

  if (t < 512) {
    int col = t;
    unsigned int bw = 0;
#pragma unroll
    for (int r = 0; r < 32; ++r)
      bw |= ((bnd[r][col >> 5] >> (col & 31)) & 1u) << r;
    cbits[((size_t)b * WPR + w) * Wn + col] = bw;
  }
}

// ---------------------------------------------------------------------------
// vertical distance from column bit-words (5 words cover rows i-64..i+95)
// ---------------------------------------------------------------------------
__device__ __forceinline__ int dv_from(unsigned int W0, unsigned int W1,
                                       unsigned int W2, unsigned int W3,
                                       unsigned int W4, int q) {
  unsigned int mLE = (q == 31) ? W2 : (W2 & ((1u << (q + 1)) - 1u));
  int up = mLE ? (q - 31 + __clz(mLE))
               : (W1 ? (q + 1 + __clz(W1))
                     : (W0 ? (q + 33 + __clz(W0)) : 255));
  unsigned int Wd = W2 >> q;
  int down = Wd ? (__ffs(Wd) - 1)
                : (W3 ? (31 - q + __ffs(W3))
                      : (W4 ? (63 - q + __ffs(W4)) : 255));
  return min(up, down);
}

// ---------------------------------------------------------------------------
// K1: chamfer window (round-9 body) + two-level spread atomic finisher:
//   level 1: block u -> grp[u&63] (64B-padded line): qv + (1<<52) count
//   level 2: group leader (count==63) -> supercnt; final leader reads the
//            64 lines with parallel lane atomics and writes the mean.
// ---------------------------------------------------------------------------
__global__ __launch_bounds__(256) void k_loss(
    const float* __restrict__ x, const unsigned int* __restrict__ mbits,
    const unsigned int* __restrict__ cbits,
    unsigned long long* __restrict__ grp, unsigned int* __restrict__ supercnt,
    float* __restrict__ out) {
  __shared__ h2 dvsA[304];  // rows (i0, i0+1)
  __shared__ h2 dvsB[304];  // rows (i0+2, i0+3)
  __shared__ float red[4];
  __shared__ unsigned long long lred[64];
  __shared__ int leader;
  const int cx = blockIdx.x, by = blockIdx.y, b = blockIdx.z;
  const int i0 = 4 * by;
  const int c0 = cx * 256;
  const int tx = threadIdx.x;
  const size_t row0 = ((size_t)b * Hn + i0) * Wn;
  const int wq = i0 >> 5, q = i0 & 31;  // q in {0,4,..,28}; q+3 <= 31
  const unsigned int* cw = cbits + (size_t)b * WPR * Wn;

  // issue x / mbits loads early; they retire under the window loop
  const int col = c0 + tx;
  float L0 = x[row0 + col];
  float L1 = x[row0 + Wn + col];
  float L2 = x[row0 + 2 * Wn + col];
  float L3 = x[row0 + 3 * Wn + col];
  const int wi = col >> 5, sh = col & 31;
  const size_t mrow = ((size_t)b * Hn + i0) * WPR + wi;
  unsigned int mw0 = mbits[mrow];
  unsigned int mw1 = mbits[mrow + WPR];
  unsigned int mw2 = mbits[mrow + 2 * WPR];
  unsigned int mw3 = mbits[mrow + 3 * WPR];

  for (int e = tx; e < 304; e += 256) {
    int c = c0 + e - RAD;
    int dv0 = 255, dv1 = 255, dv2 = 255, dv3 = 255;
    if (c >= 0 && c < Wn) {
      unsigned int W0 = (wq >= 2) ? cw[(size_t)(wq - 2) * Wn + c] : 0u;
      unsigned int W1 = (wq >= 1) ? cw[(size_t)(wq - 1) * Wn + c] : 0u;
      unsigned int W2 = cw[(size_t)wq * Wn + c];
      unsigned int W3 = (wq <= 14) ? cw[(size_t)(wq + 1) * Wn + c] : 0u;
      unsigned int W4 = (wq <= 13) ? cw[(size_t)(wq + 2) * Wn + c] : 0u;
      dv0 = dv_from(W0, W1, W2, W3, W4, q);
      dv1 = dv_from(W0, W1, W2, W3, W4, q + 1);
      dv2 = dv_from(W0, W1, W2, W3, W4, q + 2);
      dv3 = dv_from(W0, W1, W2, W3, W4, q + 3);
    }
    h2 pa, pb;
    pa.x = (_Float16)(float)dv0;
    pa.y = (_Float16)(float)dv1;
    pb.x = (_Float16)(float)dv2;
    pb.y = (_Float16)(float)dv3;
    dvsA[e] = pa;
    dvsB[e] = pb;
  }
  __syncthreads();

  const h2 A2 = {(_Float16)0.955f, (_Float16)0.955f};
  const h2 BA2 = {(_Float16)0.4143f, (_Float16)0.4143f};
  h2 a0 = {(_Float16)300.0f, (_Float16)300.0f};
  h2 a1 = a0, b0 = a0, b1 = a0;

#define STEP(k)                                                              \
  {                                                                          \
    const h2 c1 = {(_Float16)(0.955f * (k)), (_Float16)(0.955f * (k))};      \
    const h2 c2 = {(_Float16)(0.4143f * (k)), (_Float16)(0.4143f * (k))};    \
    h2 vA = __builtin_elementwise_min(dvsA[tx + RAD - (k)],                  \
                                      dvsA[tx + RAD + (k)]);                 \
    h2 vB = __builtin_elementwise_min(dvsB[tx + RAD - (k)],                  \
                                      dvsB[tx + RAD + (k)]);                 \
    h2 fA = __builtin_elementwise_max(vA * BA2 + c1, vA * A2 + c2);          \
    h2 fB = __builtin_elementwise_max(vB * BA2 + c1, vB * A2 + c2);          \
    if ((k) & 1) {                                                           \
      a1 = __builtin_elementwise_min(a1, fA);                                \
      b1 = __builtin_elementwise_min(b1, fB);                                \
    } else {                                                                 \
      a0 = __builtin_elementwise_min(a0, fA);                                \
      b0 = __builtin_elementwise_min(b0, fB);                                \
    }                                                                        \
  }

#define CHECK(kn)                                                            \
  {                                                                          \
    h2 qa = __builtin_elementwise_min(a0, a1);                               \
    h2 qb = __builtin_elementwise_min(b0, b1);                               \
    float mm = fmaxf(fmaxf((float)qa.x, (float)qa.y),                        \
                     fmaxf((float)qb.x, (float)qb.y));                       \
    for (int s = 1; s < 64; s <<= 1) mm = fmaxf(mm, __shfl_xor(mm, s, 64));  \
    if (0.955f * (float)(kn) >= mm) goto done_lab;                           \
  }

  STEP(0) STEP(1) STEP(2) STEP(3) STEP(4) STEP(5) STEP(6) STEP(7) STEP(8)
  CHECK(9)
  STEP(9) STEP(10) STEP(11) STEP(12)
  CHECK(13)
  STEP(13) STEP(14) STEP(15) STEP(16)
  CHECK(17)
  STEP(17) STEP(18) STEP(19) STEP(20)
  CHECK(21)
  STEP(21) STEP(22) STEP(23) STEP(24)
done_lab:;

  h2 amA = __builtin_elementwise_min(a0, a1);
  h2 amB = __builtin_elementwise_min(b0, b1);
  float d0 = (float)amA.x, d1 = (float)amA.y;
  float d2 = (float)amB.x, d3 = (float)amB.y;

  float w0 = __expf(d0 * (-1.0f / 3.0f)) + 0.1f;
  float w1 = __expf(d1 * (-1.0f / 3.0f)) + 0.1f;
  float w2 = __expf(d2 * (-1.0f / 3.0f)) + 0.1f;
  float w3 = __expf(d3 * (-1.0f / 3.0f)) + 0.1f;

  float t0 = (float)((mw0 >> sh) & 1u);
  float t1 = (float)((mw1 >> sh) & 1u);
  float t2 = (float)((mw2 >> sh) & 1u);
  float t3 = (float)((mw3 >> sh) & 1u);

  L0 = fminf(fmaxf(L0, -16.118095f), 16.118095f);
  L1 = fminf(fmaxf(L1, -16.118095f), 16.118095f);
  L2 = fminf(fmaxf(L2, -16.118095f), 16.118095f);
  L3 = fminf(fmaxf(L3, -16.118095f), 16.118095f);
  float bce0 = fmaxf(L0, 0.0f) - L0 * t0 + __logf(1.0f + __expf(-fabsf(L0)));
  float bce1 = fmaxf(L1, 0.0f) - L1 * t1 + __logf(1.0f + __expf(-fabsf(L1)));
  float bce2 = fmaxf(L2, 0.0f) - L2 * t2 + __logf(1.0f + __expf(-fabsf(L2)));
  float bce3 = fmaxf(L3, 0.0f) - L3 * t3 + __logf(1.0f + __expf(-fabsf(L3)));
  float val = bce0 * w0 + bce1 * w1 + bce2 * w2 + bce3 * w3;

#pragma unroll
  for (int s = 32; s; s >>= 1) val += __shfl_down(val, s, 64);
  if ((tx & 63) == 0) red[tx >> 6] = val;
  __syncthreads();

  if (tx == 0) {
    leader = 0;
    float s = red[0] + red[1] + red[2] + red[3];
    // fixed-point (2^20) partial. Per-group sum < 2^46; count in bits 52+.
    unsigned long long qv =
        (unsigned long long)__double2ll_rn((double)s * 1048576.0);
    const int u = (((b << 7) + by) << 1) + cx;  // 0..4095
    unsigned long long old =
        atomicAdd(&grp[(u & 63) * 8], qv + (1ull << 52));
    if ((old >> 52) == 63ull) {
      // group leader: our grp RMW is complete (result in hand) before this
      // issues (in-order wave issue + register dependency via the branch).
      unsigned int os = atomicAdd(supercnt, 1u);
      if (os == 63u) leader = 1;
    }
  }
  __syncthreads();

  if (leader) {
    if (tx < 64) {  // 64 parallel atomic reads (complete values guaranteed)
      unsigned long long v = atomicAdd(&grp[tx * 8], 0ull);
      lred[tx] = v & ((1ull << 52) - 1ull);
    }
    __syncthreads();
    if (tx == 0) {
      unsigned long long sum = 0ull;
#pragma unroll
      for (int i = 0; i < 64; ++i) sum += lred[i];
      out[0] =
          (float)((double)sum / (1048576.0 * (double)((size_t)Bn * Hn * Wn)));
    }
  }
}

extern "C" void kernel_launch(void* const* d_in, const int* in_sizes, int n_in,
                              void* d_out, int out_size, void* d_ws, size_t ws_size,
                              hipStream_t stream) {
  const float* inputs = (const float*)d_in[0];
  const float* targets = (const float*)d_in[1];
  float* out = (float*)d_out;

  unsigned char* ws = (unsigned char*)d_ws;
  unsigned int* mbits = (unsigned int*)ws;                        // 512 KB
  unsigned int* cbits = (unsigned int*)(ws + (512 << 10));        // 512 KB
  unsigned long long* grp = (unsigned long long*)(ws + (1 << 20));  // 4 KB
  unsigned int* supercnt = (unsigned int*)(ws + (1 << 20) + 4096);

  hipLaunchKernelGGL(k_prep, dim3(Bn * 16), dim3(1024), 0, stream, targets,
                     mbits, cbits, grp, supercnt);
  {
    dim3 blk(256, 1, 1), grd(2, Hn / 4, Bn);
    hipLaunchKernelGGL(k_loss, grd, blk, 0, stream, inputs, mbits, cbits, grp,
                       supercnt, out);
  }
}

// Round 14
// 30.312 us; speedup vs baseline: 5.7111x; 1.0182x over previous
//
#include <hip/hip_runtime.h>

#define Bn 16
#define Hn 512
#define Wn 512
#define RAD 16
#define WPR 16  // 32-bit words per row (Wn/32)

typedef _Float16 h2 __attribute__((ext_vector_type(2)));

// ---------------------------------------------------------------------------
// K0: fused binarize + morphology + transpose (proven). Block = (b, 32-row
// group w), 1024 threads. Block 0 zeroes the atomic tree.
// ---------------------------------------------------------------------------
__global__ __launch_bounds__(1024) void k_prep(
    const float* __restrict__ tgt, unsigned int* __restrict__ mbits,
    unsigned int* __restrict__ cbits, unsigned long long* __restrict__ grp,
    unsigned int* __restrict__ supercnt) {
  __shared__ int nib[4608];             // 36 rows x 128 nibbles
  __shared__ unsigned int lm[36][16];   // mask words, rows y0-2..y0+33
  __shared__ unsigned int bnd[32][17];  // boundary bits, padded
  const int w = blockIdx.x & 15, b = blockIdx.x >> 4;
  const int y0 = w * 32;
  const int t = threadIdx.x;
  const float4* t4 = (const float4*)(tgt + (size_t)b * Hn * Wn);

  if (blockIdx.x == 0) {  // zero atomic tree (visible via kernel-end release)
    if (t < 64) grp[t * 8] = 0ull;
    else if (t == 64) *supercnt = 0u;
  }

  for (int idx = t; idx < 4608; idx += 1024) {
    int r = idx >> 7, c4 = idx & 127;
    int y = y0 - 2 + r;
    int n = 0;
    if (y >= 0 && y < Hn) {
      float4 v = t4[(size_t)y * 128 + c4];
      n = (v.x > 0.5f ? 1 : 0) | (v.y > 0.5f ? 2 : 0) |
          (v.z > 0.5f ? 4 : 0) | (v.w > 0.5f ? 8 : 0);
    }
    nib[idx] = n;
  }
  __syncthreads();

  for (int idx = t; idx < 576; idx += 1024) {
    int r = idx >> 4, wi = idx & 15;
    unsigned int wv = 0;
#pragma unroll
    for (int c = 0; c < 8; ++c)
      wv |= ((unsigned int)nib[(r << 7) + (wi << 3) + c]) << (4 * c);
    lm[r][wi] = wv;
  }
  __syncthreads();

  if (t < 512) {
    int rr = t >> 4, k = t & 15;  // output row y0+rr, word k
    unsigned int m[5][5];
#pragma unroll
    for (int dy = 0; dy < 5; ++dy)
#pragma unroll
      for (int dx = 0; dx < 5; ++dx) {
        int wi = k + dx - 2;
        m[dy][dx] = (wi >= 0 && wi < 16) ? lm[rr + dy][wi] : 0u;
      }
    unsigned int hb[5][3];
#pragma unroll
    for (int dy = 0; dy < 5; ++dy)
#pragma unroll
      for (int dx = 0; dx < 3; ++dx) {
        unsigned int l = m[dy][dx], c = m[dy][dx + 1], r2 = m[dy][dx + 2];
        hb[dy][dx] = c & ((c << 1) | (l >> 31)) & ((c >> 1) | (r2 << 31));
      }
    unsigned int D = 0;
#pragma unroll
    for (int dy = 1; dy <= 3; ++dy) {
      unsigned int C[3];
#pragma unroll
      for (int dx = 0; dx < 3; ++dx) {
        unsigned int E = hb[dy - 1][dx] & hb[dy][dx] & hb[dy + 1][dx];
        C[dx] = m[dy][dx + 1] & ~E;
      }
      D |= C[1] | ((C[1] << 1) | (C[0] >> 31)) | ((C[1] >> 1) | (C[2] << 31));
    }
    bnd[rr][k] = D;
  } else {
    int task = t - 512;
    int r = task >> 4, wi = task & 15;
    mbits[((size_t)b * Hn + y0 + r) * WPR + wi] = lm[2 + r][wi];
  }
  __syncthreads();

  if (t < 512) {
    int col = t;
    unsigned int bw = 0;
#pragma unroll
    for (int r = 0; r < 32; ++r)
      bw |= ((bnd[r][col >> 5] >> (col & 31)) & 1u) << r;
    cbits[((size_t)b * WPR + w) * Wn + col] = bw;
  }
}

// ---------------------------------------------------------------------------
// vertical distance from column bit-words (5 words cover rows i-64..i+95)
// ---------------------------------------------------------------------------
__device__ __forceinline__ int dv_from(unsigned int W0, unsigned int W1,
                                       unsigned int W2, unsigned int W3,
                                       unsigned int W4, int q) {
  unsigned int mLE = (q == 31) ? W2 : (W2 & ((1u << (q + 1)) - 1u));
  int up = mLE ? (q - 31 + __clz(mLE))
               : (W1 ? (q + 1 + __clz(W1))
                     : (W0 ? (q + 33 + __clz(W0)) : 255));
  unsigned int Wd = W2 >> q;
  int down = Wd ? (__ffs(Wd) - 1)
                : (W3 ? (31 - q + __ffs(W3))
                      : (W4 ? (63 - q + __ffs(W4)) : 255));
  return min(up, down);
}

// ---------------------------------------------------------------------------
// K1: chamfer window (RAD=16, checks at 5/9/13), BCE, two-level spread
// atomic finisher (proven round-13 mechanism).
// ---------------------------------------------------------------------------
__global__ __launch_bounds__(256) void k_loss(
    const float* __restrict__ x, const unsigned int* __restrict__ mbits,
    const unsigned int* __restrict__ cbits,
    unsigned long long* __restrict__ grp, unsigned int* __restrict__ supercnt,
    float* __restrict__ out) {
  __shared__ h2 dvsA[288];  // rows (i0, i0+1)
  __shared__ h2 dvsB[288];  // rows (i0+2, i0+3)
  __shared__ float red[4];
  __shared__ unsigned long long lred[64];
  __shared__ int leader;
  const int cx = blockIdx.x, by = blockIdx.y, b = blockIdx.z;
  const int i0 = 4 * by;
  const int c0 = cx * 256;
  const int tx = threadIdx.x;
  const size_t row0 = ((size_t)b * Hn + i0) * Wn;
  const int wq = i0 >> 5, q = i0 & 31;  // q in {0,4,..,28}; q+3 <= 31
  const unsigned int* cw = cbits + (size_t)b * WPR * Wn;

  // issue x / mbits loads early; they retire under the window loop
  const int col = c0 + tx;
  float L0 = x[row0 + col];
  float L1 = x[row0 + Wn + col];
  float L2 = x[row0 + 2 * Wn + col];
  float L3 = x[row0 + 3 * Wn + col];
  const int wi = col >> 5, sh = col & 31;
  const size_t mrow = ((size_t)b * Hn + i0) * WPR + wi;
  unsigned int mw0 = mbits[mrow];
  unsigned int mw1 = mbits[mrow + WPR];
  unsigned int mw2 = mbits[mrow + 2 * WPR];
  unsigned int mw3 = mbits[mrow + 3 * WPR];

  for (int e = tx; e < 288; e += 256) {
    int c = c0 + e - RAD;
    int dv0 = 255, dv1 = 255, dv2 = 255, dv3 = 255;
    if (c >= 0 && c < Wn) {
      unsigned int W0 = (wq >= 2) ? cw[(size_t)(wq - 2) * Wn + c] : 0u;
      unsigned int W1 = (wq >= 1) ? cw[(size_t)(wq - 1) * Wn + c] : 0u;
      unsigned int W2 = cw[(size_t)wq * Wn + c];
      unsigned int W3 = (wq <= 14) ? cw[(size_t)(wq + 1) * Wn + c] : 0u;
      unsigned int W4 = (wq <= 13) ? cw[(size_t)(wq + 2) * Wn + c] : 0u;
      dv0 = dv_from(W0, W1, W2, W3, W4, q);
      dv1 = dv_from(W0, W1, W2, W3, W4, q + 1);
      dv2 = dv_from(W0, W1, W2, W3, W4, q + 2);
      dv3 = dv_from(W0, W1, W2, W3, W4, q + 3);
    }
    h2 pa, pb;
    pa.x = (_Float16)(float)dv0;
    pa.y = (_Float16)(float)dv1;
    pb.x = (_Float16)(float)dv2;
    pb.y = (_Float16)(float)dv3;
    dvsA[e] = pa;
    dvsB[e] = pb;
  }
  __syncthreads();

  const h2 A2 = {(_Float16)0.955f, (_Float16)0.955f};
  const h2 BA2 = {(_Float16)0.4143f, (_Float16)0.4143f};
  h2 a0 = {(_Float16)300.0f, (_Float16)300.0f};
  h2 a1 = a0, b0 = a0, b1 = a0;

#define STEP(k)                                                              \
  {                                                                          \
    const h2 c1 = {(_Float16)(0.955f * (k)), (_Float16)(0.955f * (k))};      \
    const h2 c2 = {(_Float16)(0.4143f * (k)), (_Float16)(0.4143f * (k))};    \
    h2 vA = __builtin_elementwise_min(dvsA[tx + RAD - (k)],                  \
                                      dvsA[tx + RAD + (k)]);                 \
    h2 vB = __builtin_elementwise_min(dvsB[tx + RAD - (k)],                  \
                                      dvsB[tx + RAD + (k)]);                 \
    h2 fA = __builtin_elementwise_max(vA * BA2 + c1, vA * A2 + c2);          \
    h2 fB = __builtin_elementwise_max(vB * BA2 + c1, vB * A2 + c2);          \
    if ((k) & 1) {                                                           \
      a1 = __builtin_elementwise_min(a1, fA);                                \
      b1 = __builtin_elementwise_min(b1, fB);                                \
    } else {                                                                 \
      a0 = __builtin_elementwise_min(a0, fA);                                \
      b0 = __builtin_elementwise_min(b0, fB);                                \
    }                                                                        \
  }

#define CHECK(kn)                                                            \
  {                                                                          \
    h2 qa = __builtin_elementwise_min(a0, a1);                               \
    h2 qb = __builtin_elementwise_min(b0, b1);                               \
    float mm = fmaxf(fmaxf((float)qa.x, (float)qa.y),                        \
                     fmaxf((float)qb.x, (float)qb.y));                       \
    for (int s = 1; s < 64; s <<= 1) mm = fmaxf(mm, __shfl_xor(mm, s, 64));  \
    if (0.955f * (float)(kn) >= mm) goto done_lab;                           \
  }

  STEP(0) STEP(1) STEP(2) STEP(3) STEP(4)
  CHECK(5)
  STEP(5) STEP(6) STEP(7) STEP(8)
  CHECK(9)
  STEP(9) STEP(10) STEP(11) STEP(12)
  CHECK(13)
  STEP(13) STEP(14) STEP(15) STEP(16)
done_lab:;

  h2 amA = __builtin_elementwise_min(a0, a1);
  h2 amB = __builtin_elementwise_min(b0, b1);
  float d0 = (float)amA.x, d1 = (float)amA.y;
  float d2 = (float)amB.x, d3 = (float)amB.y;

  float w0 = __expf(d0 * (-1.0f / 3.0f)) + 0.1f;
  float w1 = __expf(d1 * (-1.0f / 3.0f)) + 0.1f;
  float w2 = __expf(d2 * (-1.0f / 3.0f)) + 0.1f;
  float w3 = __expf(d3 * (-1.0f / 3.0f)) + 0.1f;

  float t0 = (float)((mw0 >> sh) & 1u);
  float t1 = (float)((mw1 >> sh) & 1u);
  float t2 = (float)((mw2 >> sh) & 1u);
  float t3 = (float)((mw3 >> sh) & 1u);

  L0 = fminf(fmaxf(L0, -16.118095f), 16.118095f);
  L1 = fminf(fmaxf(L1, -16.118095f), 16.118095f);
  L2 = fminf(fmaxf(L2, -16.118095f), 16.118095f);
  L3 = fminf(fmaxf(L3, -16.118095f), 16.118095f);
  float bce0 = fmaxf(L0, 0.0f) - L0 * t0 + __logf(1.0f + __expf(-fabsf(L0)));
  float bce1 = fmaxf(L1, 0.0f) - L1 * t1 + __logf(1.0f + __expf(-fabsf(L1)));
  float bce2 = fmaxf(L2, 0.0f) - L2 * t2 + __logf(1.0f + __expf(-fabsf(L2)));
  float bce3 = fmaxf(L3, 0.0f) - L3 * t3 + __logf(1.0f + __expf(-fabsf(L3)));
  float val = bce0 * w0 + bce1 * w1 + bce2 * w2 + bce3 * w3;

#pragma unroll
  for (int s = 32; s; s >>= 1) val += __shfl_down(val, s, 64);
  if ((tx & 63) == 0) red[tx >> 6] = val;
  __syncthreads();

  if (tx == 0) {
    leader = 0;
    float s = red[0] + red[1] + red[2] + red[3];
    // fixed-point (2^20) partial. Per-group sum < 2^46; count in bits 52+.
    unsigned long long qv =
        (unsigned long long)__double2ll_rn((double)s * 1048576.0);
    const int u = (((b << 7) + by) << 1) + cx;  // 0..4095
    unsigned long long old =
        atomicAdd(&grp[(u & 63) * 8], qv + (1ull << 52));
    if ((old >> 52) == 63ull) {
      unsigned int os = atomicAdd(supercnt, 1u);
      if (os == 63u) leader = 1;
    }
  }
  __syncthreads();

  if (leader) {
    if (tx < 64) {  // 64 parallel atomic reads (complete values guaranteed)
      unsigned long long v = atomicAdd(&grp[tx * 8], 0ull);
      lred[tx] = v & ((1ull << 52) - 1ull);
    }
    __syncthreads();
    if (tx == 0) {
      unsigned long long sum = 0ull;
#pragma unroll
      for (int i = 0; i < 64; ++i) sum += lred[i];
      out[0] =
          (float)((double)sum / (1048576.0 * (double)((size_t)Bn * Hn * Wn)));
    }
  }
}

extern "C" void kernel_launch(void* const* d_in, const int* in_sizes, int n_in,
                              void* d_out, int out_size, void* d_ws, size_t ws_size,
                              hipStream_t stream) {
  const float* inputs = (const float*)d_in[0];
  const float* targets = (const float*)d_in[1];
  float* out = (float*)d_out;

  unsigned char* ws = (unsigned char*)d_ws;
  unsigned int* mbits = (unsigned int*)ws;                          // 512 KB
  unsigned int* cbits = (unsigned int*)(ws + (512 << 10));          // 512 KB
  unsigned long long* grp = (unsigned long long*)(ws + (1 << 20));  // 4 KB
  unsigned int* supercnt = (unsigned int*)(ws + (1 << 20) + 4096);

  hipLaunchKernelGGL(k_prep, dim3(Bn * 16), dim3(1024), 0, stream, targets,
                     mbits, cbits, grp, supercnt);
  {
    dim3 blk(256, 1, 1), grd(2, Hn / 4, Bn);
    hipLaunchKernelGGL(k_loss, grd, blk, 0, stream, inputs, mbits, cbits, grp,
                       supercnt, out);
  }
}

// Round 15
// 28.924 us; speedup vs baseline: 5.9852x; 1.0480x over previous
//
#include <hip/hip_runtime.h>

#define Bn 16
#define Hn 512
#define Wn 512
#define RAD 16
#define WPR 16  // 32-bit words per row (Wn/32)

typedef _Float16 h2 __attribute__((ext_vector_type(2)));

// ---------------------------------------------------------------------------
// K0: fused binarize + morphology + transpose (proven). Block = (b, 32-row
// group w), 1024 threads. Block 0 zeroes the atomic tree.
// ---------------------------------------------------------------------------
__global__ __launch_bounds__(1024) void k_prep(
    const float* __restrict__ tgt, unsigned int* __restrict__ mbits,
    unsigned int* __restrict__ cbits, unsigned long long* __restrict__ grp,
    unsigned int* __restrict__ supercnt) {
  __shared__ int nib[4608];             // 36 rows x 128 nibbles
  __shared__ unsigned int lm[36][16];   // mask words, rows y0-2..y0+33
  __shared__ unsigned int bnd[32][17];  // boundary bits, padded
  const int w = blockIdx.x & 15, b = blockIdx.x >> 4;
  const int y0 = w * 32;
  const int t = threadIdx.x;
  const float4* t4 = (const float4*)(tgt + (size_t)b * Hn * Wn);

  if (blockIdx.x == 0) {  // zero atomic tree (visible via kernel-end release)
    if (t < 64) grp[t * 8] = 0ull;
    else if (t == 64) *supercnt = 0u;
  }

  for (int idx = t; idx < 4608; idx += 1024) {
    int r = idx >> 7, c4 = idx & 127;
    int y = y0 - 2 + r;
    int n = 0;
    if (y >= 0 && y < Hn) {
      float4 v = t4[(size_t)y * 128 + c4];
      n = (v.x > 0.5f ? 1 : 0) | (v.y > 0.5f ? 2 : 0) |
          (v.z > 0.5f ? 4 : 0) | (v.w > 0.5f ? 8 : 0);
    }
    nib[idx] = n;
  }
  __syncthreads();

  for (int idx = t; idx < 576; idx += 1024) {
    int r = idx >> 4, wi = idx & 15;
    unsigned int wv = 0;
#pragma unroll
    for (int c = 0; c < 8; ++c)
      wv |= ((unsigned int)nib[(r << 7) + (wi << 3) + c]) << (4 * c);
    lm[r][wi] = wv;
  }
  __syncthreads();

  if (t < 512) {
    int rr = t >> 4, k = t & 15;  // output row y0+rr, word k
    unsigned int m[5][5];
#pragma unroll
    for (int dy = 0; dy < 5; ++dy)
#pragma unroll
      for (int dx = 0; dx < 5; ++dx) {
        int wi = k + dx - 2;
        m[dy][dx] = (wi >= 0 && wi < 16) ? lm[rr + dy][wi] : 0u;
      }
    unsigned int hb[5][3];
#pragma unroll
    for (int dy = 0; dy < 5; ++dy)
#pragma unroll
      for (int dx = 0; dx < 3; ++dx) {
        unsigned int l = m[dy][dx], c = m[dy][dx + 1], r2 = m[dy][dx + 2];
        hb[dy][dx] = c & ((c << 1) | (l >> 31)) & ((c >> 1) | (r2 << 31));
      }
    unsigned int D = 0;
#pragma unroll
    for (int dy = 1; dy <= 3; ++dy) {
      unsigned int C[3];
#pragma unroll
      for (int dx = 0; dx < 3; ++dx) {
        unsigned int E = hb[dy - 1][dx] & hb[dy][dx] & hb[dy + 1][dx];
        C[dx] = m[dy][dx + 1] & ~E;
      }
      D |= C[1] | ((C[1] << 1) | (C[0] >> 31)) | ((C[1] >> 1) | (C[2] << 31));
    }
    bnd[rr][k] = D;
  } else {
    int task = t - 512;
    int r = task >> 4, wi = task & 15;
    mbits[((size_t)b * Hn + y0 + r) * WPR + wi] = lm[2 + r][wi];
  }
  __syncthreads();

  if (t < 512) {
    int col = t;
    unsigned int bw = 0;
#pragma unroll
    for (int r = 0; r < 32; ++r)
      bw |= ((bnd[r][col >> 5] >> (col & 31)) & 1u) << r;
    cbits[((size_t)b * WPR + w) * Wn + col] = bw;
  }
}

// ---------------------------------------------------------------------------
// vertical distance from column bit-words (5 words cover rows i-64..i+95)
// ---------------------------------------------------------------------------
__device__ __forceinline__ int dv_from(unsigned int W0, unsigned int W1,
                                       unsigned int W2, unsigned int W3,
                                       unsigned int W4, int q) {
  unsigned int mLE = (q == 31) ? W2 : (W2 & ((1u << (q + 1)) - 1u));
  int up = mLE ? (q - 31 + __clz(mLE))
               : (W1 ? (q + 1 + __clz(W1))
                     : (W0 ? (q + 33 + __clz(W0)) : 255));
  unsigned int Wd = W2 >> q;
  int down = Wd ? (__ffs(Wd) - 1)
                : (W3 ? (31 - q + __ffs(W3))
                      : (W4 ? (63 - q + __ffs(W4)) : 255));
  return min(up, down);
}

// ---------------------------------------------------------------------------
// K1: chamfer window, 8 rows/block (four h2 pairs), wave-uniform early exit,
// BCE, two-level spread atomic finisher. 2048 blocks.
// ---------------------------------------------------------------------------
__global__ __launch_bounds__(256) void k_loss(
    const float* __restrict__ x, const unsigned int* __restrict__ mbits,
    const unsigned int* __restrict__ cbits,
    unsigned long long* __restrict__ grp, unsigned int* __restrict__ supercnt,
    float* __restrict__ out) {
  __shared__ h2 dvsA[288];  // rows (i0,   i0+1)
  __shared__ h2 dvsB[288];  // rows (i0+2, i0+3)
  __shared__ h2 dvsC[288];  // rows (i0+4, i0+5)
  __shared__ h2 dvsD[288];  // rows (i0+6, i0+7)
  __shared__ float red[4];
  __shared__ unsigned long long lred[64];
  __shared__ int leader;
  const int cx = blockIdx.x, by = blockIdx.y, b = blockIdx.z;
  const int i0 = 8 * by;
  const int c0 = cx * 256;
  const int tx = threadIdx.x;
  const size_t row0 = ((size_t)b * Hn + i0) * Wn;
  const int wq = i0 >> 5, q = i0 & 31;  // q in {0,8,16,24}; q+7 <= 31
  const unsigned int* cw = cbits + (size_t)b * WPR * Wn;

  // issue x / mbits loads early; they retire under the prologue/window
  const int col = c0 + tx;
  float L[8];
#pragma unroll
  for (int r = 0; r < 8; ++r) L[r] = x[row0 + (size_t)r * Wn + col];
  const int wi = col >> 5, sh = col & 31;
  const size_t mrow = ((size_t)b * Hn + i0) * WPR + wi;
  unsigned int mw[8];
#pragma unroll
  for (int r = 0; r < 8; ++r) mw[r] = mbits[mrow + (size_t)r * WPR];

  for (int e = tx; e < 288; e += 256) {
    int c = c0 + e - RAD;
    int dv[8];
#pragma unroll
    for (int r = 0; r < 8; ++r) dv[r] = 255;
    if (c >= 0 && c < Wn) {
      unsigned int W0 = (wq >= 2) ? cw[(size_t)(wq - 2) * Wn + c] : 0u;
      unsigned int W1 = (wq >= 1) ? cw[(size_t)(wq - 1) * Wn + c] : 0u;
      unsigned int W2 = cw[(size_t)wq * Wn + c];
      unsigned int W3 = (wq <= 14) ? cw[(size_t)(wq + 1) * Wn + c] : 0u;
      unsigned int W4 = (wq <= 13) ? cw[(size_t)(wq + 2) * Wn + c] : 0u;
#pragma unroll
      for (int r = 0; r < 8; ++r) dv[r] = dv_from(W0, W1, W2, W3, W4, q + r);
    }
    h2 p;
    p.x = (_Float16)(float)dv[0]; p.y = (_Float16)(float)dv[1]; dvsA[e] = p;
    p.x = (_Float16)(float)dv[2]; p.y = (_Float16)(float)dv[3]; dvsB[e] = p;
    p.x = (_Float16)(float)dv[4]; p.y = (_Float16)(float)dv[5]; dvsC[e] = p;
    p.x = (_Float16)(float)dv[6]; p.y = (_Float16)(float)dv[7]; dvsD[e] = p;
  }
  __syncthreads();

  const h2 A2 = {(_Float16)0.955f, (_Float16)0.955f};
  const h2 BA2 = {(_Float16)0.4143f, (_Float16)0.4143f};
  h2 a0 = {(_Float16)300.0f, (_Float16)300.0f};
  h2 a1 = a0, b0 = a0, b1 = a0, c0a = a0, c1a = a0, d0a = a0, d1a = a0;

#define STEP(k)                                                              \
  {                                                                          \
    const h2 c1 = {(_Float16)(0.955f * (k)), (_Float16)(0.955f * (k))};      \
    const h2 c2 = {(_Float16)(0.4143f * (k)), (_Float16)(0.4143f * (k))};    \
    h2 vA = __builtin_elementwise_min(dvsA[tx + RAD - (k)],                  \
                                      dvsA[tx + RAD + (k)]);                 \
    h2 vB = __builtin_elementwise_min(dvsB[tx + RAD - (k)],                  \
                                      dvsB[tx + RAD + (k)]);                 \
    h2 vC = __builtin_elementwise_min(dvsC[tx + RAD - (k)],                  \
                                      dvsC[tx + RAD + (k)]);                 \
    h2 vD = __builtin_elementwise_min(dvsD[tx + RAD - (k)],                  \
                                      dvsD[tx + RAD + (k)]);                 \
    h2 fA = __builtin_elementwise_max(vA * BA2 + c1, vA * A2 + c2);          \
    h2 fB = __builtin_elementwise_max(vB * BA2 + c1, vB * A2 + c2);          \
    h2 fC = __builtin_elementwise_max(vC * BA2 + c1, vC * A2 + c2);          \
    h2 fD = __builtin_elementwise_max(vD * BA2 + c1, vD * A2 + c2);          \
    if ((k) & 1) {                                                           \
      a1 = __builtin_elementwise_min(a1, fA);                                \
      b1 = __builtin_elementwise_min(b1, fB);                                \
      c1a = __builtin_elementwise_min(c1a, fC);                              \
      d1a = __builtin_elementwise_min(d1a, fD);                              \
    } else {                                                                 \
      a0 = __builtin_elementwise_min(a0, fA);                                \
      b0 = __builtin_elementwise_min(b0, fB);                                \
      c0a = __builtin_elementwise_min(c0a, fC);                              \
      d0a = __builtin_elementwise_min(d0a, fD);                              \
    }                                                                        \
  }

#define CHECK(kn)                                                            \
  {                                                                          \
    h2 qa = __builtin_elementwise_min(a0, a1);                               \
    h2 qb = __builtin_elementwise_min(b0, b1);                               \
    h2 qc = __builtin_elementwise_min(c0a, c1a);                             \
    h2 qd = __builtin_elementwise_min(d0a, d1a);                             \
    h2 qq = __builtin_elementwise_min(__builtin_elementwise_min(qa, qb),     \
                                      __builtin_elementwise_min(qc, qd));    \
    float mm = fmaxf((float)qq.x, (float)qq.y);                              \
    for (int s = 1; s < 64; s <<= 1) mm = fmaxf(mm, __shfl_xor(mm, s, 64));  \
    if (0.955f * (float)(kn) >= mm) goto done_lab;                           \
  }

  STEP(0) STEP(1) STEP(2) STEP(3) STEP(4)
  CHECK(5)
  STEP(5) STEP(6) STEP(7) STEP(8)
  CHECK(9)
  STEP(9) STEP(10) STEP(11) STEP(12)
  CHECK(13)
  STEP(13) STEP(14) STEP(15) STEP(16)
done_lab:;

  {
    h2 am[4];
    am[0] = __builtin_elementwise_min(a0, a1);
    am[1] = __builtin_elementwise_min(b0, b1);
    am[2] = __builtin_elementwise_min(c0a, c1a);
    am[3] = __builtin_elementwise_min(d0a, d1a);

    float val = 0.0f;
#pragma unroll
    for (int p = 0; p < 4; ++p) {
      float dlo = (float)am[p].x, dhi = (float)am[p].y;
      float wlo = __expf(dlo * (-1.0f / 3.0f)) + 0.1f;
      float whi = __expf(dhi * (-1.0f / 3.0f)) + 0.1f;
      float tlo = (float)((mw[2 * p] >> sh) & 1u);
      float thi = (float)((mw[2 * p + 1] >> sh) & 1u);
      float Llo = fminf(fmaxf(L[2 * p], -16.118095f), 16.118095f);
      float Lhi = fminf(fmaxf(L[2 * p + 1], -16.118095f), 16.118095f);
      float blo = fmaxf(Llo, 0.0f) - Llo * tlo +
                  __logf(1.0f + __expf(-fabsf(Llo)));
      float bhi = fmaxf(Lhi, 0.0f) - Lhi * thi +
                  __logf(1.0f + __expf(-fabsf(Lhi)));
      val += blo * wlo + bhi * whi;
    }

#pragma unroll
    for (int s = 32; s; s >>= 1) val += __shfl_down(val, s, 64);
    if ((tx & 63) == 0) red[tx >> 6] = val;
  }
  __syncthreads();

  if (tx == 0) {
    leader = 0;
    float s = red[0] + red[1] + red[2] + red[3];
    // fixed-point (2^20) partial. Per-group sum < 2^41; count in bits 52+.
    unsigned long long qv =
        (unsigned long long)__double2ll_rn((double)s * 1048576.0);
    const int u = (((b << 6) + by) << 1) + cx;  // 0..2047
    unsigned long long old = atomicAdd(&grp[(u & 63) * 8], qv + (1ull << 52));
    if ((old >> 52) == 31ull) {  // 32 blocks per group
      unsigned int os = atomicAdd(supercnt, 1u);
      if (os == 63u) leader = 1;
    }
  }
  __syncthreads();

  if (leader) {
    if (tx < 64) {  // 64 parallel atomic reads (complete values guaranteed)
      unsigned long long v = atomicAdd(&grp[tx * 8], 0ull);
      lred[tx] = v & ((1ull << 52) - 1ull);
    }
    __syncthreads();
    if (tx == 0) {
      unsigned long long sum = 0ull;
#pragma unroll
      for (int i = 0; i < 64; ++i) sum += lred[i];
      out[0] =
          (float)((double)sum / (1048576.0 * (double)((size_t)Bn * Hn * Wn)));
    }
  }
}

extern "C" void kernel_launch(void* const* d_in, const int* in_sizes, int n_in,
                              void* d_out, int out_size, void* d_ws, size_t ws_size,
                              hipStream_t stream) {
  const float* inputs = (const float*)d_in[0];
  const float* targets = (const float*)d_in[1];
  float* out = (float*)d_out;

  unsigned char* ws = (unsigned char*)d_ws;
  unsigned int* mbits = (unsigned int*)ws;                          // 512 KB
  unsigned int* cbits = (unsigned int*)(ws + (512 << 10));          // 512 KB
  unsigned long long* grp = (unsigned long long*)(ws + (1 << 20));  // 4 KB
  unsigned int* supercnt = (unsigned int*)(ws + (1 << 20) + 4096);

  hipLaunchKernelGGL(k_prep, dim3(Bn * 16), dim3(1024), 0, stream, targets,
                     mbits, cbits, grp, supercnt);
  {
    dim3 blk(256, 1, 1), grd(2, Hn / 8, Bn);
    hipLaunchKernelGGL(k_loss, grd, blk, 0, stream, inputs, mbits, cbits, grp,
                       supercnt, out);
  }
}